// Round 10
// baseline (9276.162 us; speedup 1.0000x reference)
//
#include <hip/hip_runtime.h>

typedef __bf16 bf16;
typedef bf16 bf16x8 __attribute__((ext_vector_type(8)));
typedef bf16 bf16x4 __attribute__((ext_vector_type(4)));
typedef float f32x4 __attribute__((ext_vector_type(4)));

#define B_ 4096
#define S_ 32
#define H_ 512
#define NL_ 6
constexpr size_t TOK = (size_t)B_ * S_;     // 131072 tokens

typedef __attribute__((address_space(1))) void* gas_t;
typedef __attribute__((address_space(3))) void* las_t;

__device__ __forceinline__ void async16(bf16* lds, const bf16* g) {
    // 16B per lane, LDS dest = wave-uniform base + lane*16
    __builtin_amdgcn_global_load_lds((gas_t)g, (las_t)lds, 16, 0, 0);
}

// ---------------- GEMM: C[M,N] = act(A[M,K(lda)] @ W[N,K]^T + bias) ----------------
// 128x128 tile, BK=64, 4 waves of 4x4 16x16x32 bf16 MFMA frags.
// XCD-aware remap: all n-blocks of one m-row land on one XCD (id%8 round-robin
// heuristic) -> A-tile fetched ~once per XCD. [verified r6: FETCH 135->28 MB]
template<bool RELU>
__global__ __launch_bounds__(256, 2) void gemm_kernel(
    const bf16* __restrict__ A, int lda, const bf16* __restrict__ W,
    const float* __restrict__ bias,
    bf16* C, int N, int K)
{
    __shared__ __align__(16) bf16 As[128 * 64];
    __shared__ __align__(16) bf16 Bs[128 * 64];
    const int tid  = threadIdx.x;
    const int lane = tid & 63, wid = tid >> 6;
    int m_idx, n_idx;
    {
        const int nb = gridDim.x, mgd = gridDim.y;
        if ((mgd & 7) == 0) {
            int id  = blockIdx.y * nb + blockIdx.x;
            int xcd = id & 7, j = id >> 3;
            n_idx = j % nb;
            m_idx = (j / nb) * 8 + xcd;     // same-m group stays on one XCD
        } else { m_idx = blockIdx.y; n_idx = blockIdx.x; }
    }
    const int m0 = m_idx << 7, n0 = n_idx << 7;
    const int r = lane & 15, quad = lane >> 4;
    const int wm = (wid & 1) << 6, wn = (wid >> 1) << 6;

    f32x4 acc[4][4];
#pragma unroll
    for (int i = 0; i < 4; ++i)
#pragma unroll
        for (int j = 0; j < 4; ++j) acc[i][j] = {0.f, 0.f, 0.f, 0.f};

    const int nkt = K >> 6;
    for (int kt = 0; kt < nkt; ++kt) {
        const int k0 = kt << 6;
#pragma unroll
        for (int p = 0; p < 4; ++p) {
            int q   = p * 256 + tid;
            int row = q >> 3;
            int cg  = (q & 7) ^ (row & 7);
            async16(&As[(size_t)(p * 256 + wid * 64) * 8],
                    A + (size_t)(m0 + row) * lda + k0 + cg * 8);
            async16(&Bs[(size_t)(p * 256 + wid * 64) * 8],
                    W + (size_t)(n0 + row) * K + k0 + cg * 8);
        }
        __syncthreads();
#pragma unroll
        for (int ks = 0; ks < 2; ++ks) {
            bf16x8 af[4], bfr[4];
#pragma unroll
            for (int mi = 0; mi < 4; ++mi) {
                int row  = wm + mi * 16 + r;
                int slot = (ks * 4 + quad) ^ (row & 7);
                af[mi] = *(const bf16x8*)&As[row * 64 + slot * 8];
            }
#pragma unroll
            for (int ni = 0; ni < 4; ++ni) {
                int row  = wn + ni * 16 + r;
                int slot = (ks * 4 + quad) ^ (row & 7);
                bfr[ni] = *(const bf16x8*)&Bs[row * 64 + slot * 8];
            }
#pragma unroll
            for (int mi = 0; mi < 4; ++mi)
#pragma unroll
                for (int ni = 0; ni < 4; ++ni)
                    acc[mi][ni] = __builtin_amdgcn_mfma_f32_16x16x32_bf16(
                        af[mi], bfr[ni], acc[mi][ni], 0, 0, 0);
        }
        __syncthreads();
    }
    // epilogue: C/D layout col = lane&15, row = quad*4 + reg
#pragma unroll
    for (int ni = 0; ni < 4; ++ni) {
        int col  = n0 + wn + ni * 16 + r;
        float bv = bias[col];
#pragma unroll
        for (int mi = 0; mi < 4; ++mi) {
            int mrow = m0 + wm + mi * 16 + quad * 4;
#pragma unroll
            for (int rr = 0; rr < 4; ++rr) {
                size_t idx = (size_t)(mrow + rr) * N + col;
                float v = acc[mi][ni][rr] + bv;
                if (RELU) v = fmaxf(v, 0.f);
                C[idx] = (bf16)v;
            }
        }
    }
}

// ------- GEMM + residual + LayerNorm fused: x = LN(A@W^T + bias + x) -------
// M=64 tile, FULL N=512 per block, BK=32 (r10): LDS 38 KB -> 3-4 blocks/CU
// (was 74 KB -> 2) so per-iter barrier drains overlap across blocks.
// Pair-stripe swizzle: rows 2p,2p+1 share a 128B stripe; logical chunk
// q = (row&1)*4 + kchunk lives at phys slot q^(p&7) -> frag ds_read_b128
// covers each stripe's 8 chunks bijectively = conflict-free.
// 4 waves; wave w owns n-strip [w*128, w*128+128): acc[4][8].
__global__ __launch_bounds__(256, 2) void gemm_ln_kernel(
    const bf16* __restrict__ A, int lda, const bf16* __restrict__ W,
    const float* __restrict__ bias, bf16* x,
    const float* __restrict__ lnw, const float* __restrict__ lnb, int K)
{
    __shared__ __align__(16) bf16 As[64 * 32];    // 4 KB (32 stripes x 8 chunks)
    __shared__ __align__(16) bf16 Ws[512 * 32];   // 32 KB (256 stripes x 8 chunks)
    __shared__ float ps[64][4], ps2[64][4];       // 2 KB
    const int tid  = threadIdx.x;
    const int lane = tid & 63, wid = tid >> 6;
    const int m0 = blockIdx.x << 6;
    const int r = lane & 15, quad = lane >> 4;
    const int wn = wid << 7;

    f32x4 acc[4][8];
#pragma unroll
    for (int i = 0; i < 4; ++i)
#pragma unroll
        for (int j = 0; j < 8; ++j) acc[i][j] = {0.f, 0.f, 0.f, 0.f};

    const int nkt = K >> 5;
    for (int kt = 0; kt < nkt; ++kt) {
        const int k0 = kt << 5;
        {   // A tile: 64 rows x 4 chunks = 256 ops (1/thread), pair-stripe layout
            int p  = tid >> 3, s = tid & 7;
            int lg = s ^ (p & 7);
            int row = 2 * p + (lg >> 2), kc = lg & 3;
            async16(&As[(size_t)(wid * 64) * 8],
                    A + (size_t)(m0 + row) * lda + k0 + kc * 8);
        }
#pragma unroll
        for (int i = 0; i < 8; ++i) {   // W tile: 512 rows x 4 chunks = 2048 ops
            int q  = i * 256 + tid;
            int p  = q >> 3, s = q & 7;
            int lg = s ^ (p & 7);
            int row = 2 * p + (lg >> 2), kc = lg & 3;
            async16(&Ws[(size_t)(i * 256 + wid * 64) * 8],
                    W + (size_t)row * K + k0 + kc * 8);
        }
        __syncthreads();
        {
            bf16x8 af[4], wf[8];
#pragma unroll
            for (int mi = 0; mi < 4; ++mi) {
                int row = mi * 16 + r;
                int p = row >> 1;
                int s = (((row & 1) << 2) + quad) ^ (p & 7);
                af[mi] = *(const bf16x8*)&As[(p * 8 + s) * 8];
            }
#pragma unroll
            for (int ni = 0; ni < 8; ++ni) {
                int row = wn + ni * 16 + r;
                int p = row >> 1;
                int s = (((row & 1) << 2) + quad) ^ (p & 7);
                wf[ni] = *(const bf16x8*)&Ws[(p * 8 + s) * 8];
            }
#pragma unroll
            for (int mi = 0; mi < 4; ++mi)
#pragma unroll
                for (int ni = 0; ni < 8; ++ni)
                    acc[mi][ni] = __builtin_amdgcn_mfma_f32_16x16x32_bf16(
                        af[mi], wf[ni], acc[mi][ni], 0, 0, 0);
        }
        __syncthreads();
    }

    // ---- phase 1: v = gemm + bias + residual; per-row partial sums ----
#pragma unroll
    for (int mi = 0; mi < 4; ++mi)
#pragma unroll
        for (int rr = 0; rr < 4; ++rr) {
            int row  = mi * 16 + quad * 4 + rr;      // 0..63
            float s = 0.f, s2 = 0.f;
#pragma unroll
            for (int ni = 0; ni < 8; ++ni) {
                int col = wn + ni * 16 + r;
                float v = acc[mi][ni][rr] + bias[col]
                        + (float)x[(size_t)(m0 + row) * H_ + col];
                acc[mi][ni][rr] = v;
                s += v; s2 += v * v;
            }
#pragma unroll
            for (int off = 8; off >= 1; off >>= 1) {
                s  += __shfl_xor(s,  off, 16);
                s2 += __shfl_xor(s2, off, 16);
            }
            if (r == 0) { ps[row][wid] = s; ps2[row][wid] = s2; }
        }
    __syncthreads();

    // ---- phase 2: normalize + write ----
#pragma unroll
    for (int mi = 0; mi < 4; ++mi)
#pragma unroll
        for (int rr = 0; rr < 4; ++rr) {
            int row = mi * 16 + quad * 4 + rr;
            float s  = ps[row][0] + ps[row][1] + ps[row][2] + ps[row][3];
            float s2 = ps2[row][0] + ps2[row][1] + ps2[row][2] + ps2[row][3];
            float mu  = s * (1.f / 512.f);
            float var = s2 * (1.f / 512.f) - mu * mu;
            float inv = rsqrtf(var + 1e-5f);
#pragma unroll
            for (int ni = 0; ni < 8; ++ni) {
                int col = wn + ni * 16 + r;
                float v = (acc[mi][ni][rr] - mu) * inv * lnw[col] + lnb[col];
                x[(size_t)(m0 + row) * H_ + col] = (bf16)v;
            }
        }
}

// ---------------- Attention: one wave per (b,h), S=32, HD=64 ----------------
// Round-6 version (global V gather; LDS-transpose variant had unfixable 8-way
// bank conflicts because async16 forbids padding the staged layout).
__global__ __launch_bounds__(256) void attn_kernel(bf16* qkv)
{
    __shared__ __align__(16) bf16 Pl[4][32][40];  // padded rows (80B) -> 2-way only
    __shared__ float rs[4][32];
    const int tid = threadIdx.x;
    const int lane = tid & 63, wid = tid >> 6;
    const int pair = blockIdx.x * 4 + wid;   // b_local*8 + h
    const int b = pair >> 3, h = pair & 7;
    const int r = lane & 15, quad = lane >> 4;
    bf16* base = qkv + (size_t)b * 32 * 1536 + h * 64;

    // Q as A-operand, K as B-operand (both: row = lane&15, k = quad*8+j)
    bf16x8 aq[2][2], bk[2][2];
#pragma unroll
    for (int t = 0; t < 2; ++t)
#pragma unroll
        for (int ks = 0; ks < 2; ++ks) {
            aq[t][ks] = *(const bf16x8*)(base +       (size_t)(t * 16 + r) * 1536 + ks * 32 + quad * 8);
            bk[t][ks] = *(const bf16x8*)(base + 512 + (size_t)(t * 16 + r) * 1536 + ks * 32 + quad * 8);
        }
    f32x4 sc[2][2];
#pragma unroll
    for (int mt = 0; mt < 2; ++mt)
#pragma unroll
        for (int nt = 0; nt < 2; ++nt) sc[mt][nt] = {0.f, 0.f, 0.f, 0.f};
#pragma unroll
    for (int mt = 0; mt < 2; ++mt)
#pragma unroll
        for (int nt = 0; nt < 2; ++nt)
#pragma unroll
            for (int ks = 0; ks < 2; ++ks)
                sc[mt][nt] = __builtin_amdgcn_mfma_f32_16x16x32_bf16(
                    aq[mt][ks], bk[nt][ks], sc[mt][nt], 0, 0, 0);

    // softmax over j (row i = mt*16 + quad*4 + rr lives in one 16-lane group)
#pragma unroll
    for (int mt = 0; mt < 2; ++mt)
#pragma unroll
        for (int rr = 0; rr < 4; ++rr) {
            int i = mt * 16 + quad * 4 + rr;
            float v0 = sc[mt][0][rr] * 0.125f;
            float v1 = sc[mt][1][rr] * 0.125f;
            float mx = fmaxf(v0, v1);
#pragma unroll
            for (int off = 8; off >= 1; off >>= 1) mx = fmaxf(mx, __shfl_xor(mx, off, 16));
            float e0 = __expf(v0 - mx), e1 = __expf(v1 - mx);
            float s = e0 + e1;
#pragma unroll
            for (int off = 8; off >= 1; off >>= 1) s += __shfl_xor(s, off, 16);
            Pl[wid][i][r]      = (bf16)e0;
            Pl[wid][i][r + 16] = (bf16)e1;
            if (r == 0) rs[wid][i] = s;
        }
    __syncthreads();

    // O^T = V^T (A-op, gathered from global) x P^T (B-op from LDS)
    const bf16* vb = base + 1024;
    bf16x8 av[4];
#pragma unroll
    for (int mt = 0; mt < 4; ++mt)
#pragma unroll
        for (int jj = 0; jj < 8; ++jj)
            av[mt][jj] = vb[(size_t)(quad * 8 + jj) * 1536 + mt * 16 + r];
    bf16x8 bp[2];
#pragma unroll
    for (int nt = 0; nt < 2; ++nt)
        bp[nt] = *(const bf16x8*)&Pl[wid][nt * 16 + r][quad * 8];
    f32x4 oc[4][2];
#pragma unroll
    for (int mt = 0; mt < 4; ++mt)
#pragma unroll
        for (int nt = 0; nt < 2; ++nt) oc[mt][nt] = {0.f, 0.f, 0.f, 0.f};
#pragma unroll
    for (int mt = 0; mt < 4; ++mt)
#pragma unroll
        for (int nt = 0; nt < 2; ++nt)
            oc[mt][nt] = __builtin_amdgcn_mfma_f32_16x16x32_bf16(av[mt], bp[nt], oc[mt][nt], 0, 0, 0);

    float inv0 = 1.f / rs[wid][r];
    float inv1 = 1.f / rs[wid][r + 16];
    bf16* ob = base;                          // write O into the q-slot, stride 1536
#pragma unroll
    for (int mt = 0; mt < 4; ++mt)
#pragma unroll
        for (int nt = 0; nt < 2; ++nt) {
            int i = nt * 16 + r;              // query index
            float invv = nt ? inv1 : inv0;
            bf16x4 pk;
#pragma unroll
            for (int rr = 0; rr < 4; ++rr) pk[rr] = (bf16)(oc[mt][nt][rr] * invv);
            *(bf16x4*)(ob + (size_t)i * 1536 + mt * 16 + quad * 4) = pk;  // d = mt*16+quad*4+rr
        }
}

// ---------------- Embedding sum -> bf16 x (chunk-local), 4 rows/block ----------------
__global__ __launch_bounds__(256) void embed_kernel(
    const int* __restrict__ seq, const int* __restrict__ lid,
    const float* __restrict__ et, const float* __restrict__ lt, const float* __restrict__ pt,
    bf16* __restrict__ x, int t0)
{
    const int lane = threadIdx.x & 63, wid = threadIdx.x >> 6;
    const int rowl = blockIdx.x * 4 + wid;     // chunk-local token
    const int rowg = t0 + rowl;                // global token = b*32 + s
    const int b = rowg >> 5, s = rowg & 31;
    const int e = seq[rowg];
    const int l = lid[b];
    const float* pe = et + (size_t)e * H_ + lane * 8;
    const float* pl = lt + (size_t)l * H_ + lane * 8;
    const float* pp = pt + (size_t)s * H_ + lane * 8;
    bf16x8 o8;
#pragma unroll
    for (int j = 0; j < 8; ++j) o8[j] = (bf16)(pe[j] + pl[j] + pp[j]);
    *(bf16x8*)(x + (size_t)rowl * H_ + lane * 8) = o8;
}

// ---------------- Weight convert: all 4 arrays in one dispatch ----------------
__global__ __launch_bounds__(256) void cvt4_kernel(
    const float* __restrict__ a0, bf16* __restrict__ o0, int n0,
    const float* __restrict__ a1, bf16* __restrict__ o1, int n1,
    const float* __restrict__ a2, bf16* __restrict__ o2, int n2,
    const float* __restrict__ a3, bf16* __restrict__ o3, int n3)
{
    int i = blockIdx.x * 256 + threadIdx.x;
    if (i < n0) { o0[i] = (bf16)a0[i]; }
    i -= n0;
    if (i >= 0 && i < n1) { o1[i] = (bf16)a1[i]; }
    i -= n1;
    if (i >= 0 && i < n2) { o2[i] = (bf16)a2[i]; }
    i -= n2;
    if (i >= 0 && i < n3) { o3[i] = (bf16)a3[i]; }
}

// ---------------- Head + confidence (chunk-local x, global b = b0 + blockIdx.x) -------------
__global__ __launch_bounds__(256) void head_kernel(
    const bf16* __restrict__ x, const int* __restrict__ lid,
    const float* __restrict__ hw, const float* __restrict__ hb,
    const float* __restrict__ cw, const float* __restrict__ cb, float* __restrict__ out, int b0)
{
    __shared__ float last[512];
    __shared__ float part[256];
    const int bl = blockIdx.x, tid = threadIdx.x;
    const int b = b0 + bl;
    const size_t row = (size_t)bl * 32 + 31;
    for (int c = tid; c < 512; c += 256) last[c] = (float)x[row * 512 + c];
    __syncthreads();
    int l = lid[b];
    int hidx = (l & 1) ? ((l - 1) >> 1) : 0;
    int e = tid & 127, half = tid >> 7;
    const float* wr = hw + ((size_t)hidx * 128 + e) * 512 + half * 256;
    float s = 0.f;
    for (int k = 0; k < 256; ++k) s += last[half * 256 + k] * wr[k];
    part[tid] = s;
    __syncthreads();
    if (tid < 128) out[(size_t)b * 128 + tid] = part[tid] + part[tid + 128] + hb[hidx * 128 + tid];
    if (tid >= 128 && tid < 192) {      // wave 2: confidence
        int ln = tid - 128;
        float cs = 0.f;
#pragma unroll
        for (int k = 0; k < 8; ++k) cs += last[ln * 8 + k] * cw[ln * 8 + k];
#pragma unroll
        for (int off = 32; off >= 1; off >>= 1) cs += __shfl_xor(cs, off, 64);
        if (ln == 0) out[(size_t)B_ * 128 + b] = 1.f / (1.f + __expf(-(cs + cb[0])));
    }
}

extern "C" void kernel_launch(void* const* d_in, const int* in_sizes, int n_in,
                              void* d_out, int out_size, void* d_ws, size_t ws_size,
                              hipStream_t stream)
{
    const int*   seq          = (const int*)d_in[0];
    const int*   lid          = (const int*)d_in[1];
    const float* expert_table = (const float*)d_in[2];
    const float* layer_table  = (const float*)d_in[3];
    const float* pos_table    = (const float*)d_in[4];
    const float* qkv_w        = (const float*)d_in[5];
    const float* qkv_b        = (const float*)d_in[6];
    const float* out_w        = (const float*)d_in[7];
    const float* out_b        = (const float*)d_in[8];
    const float* ln1_w        = (const float*)d_in[9];
    const float* ln1_b        = (const float*)d_in[10];
    const float* ff1_w        = (const float*)d_in[11];
    const float* ff1_b        = (const float*)d_in[12];
    const float* ff2_w        = (const float*)d_in[13];
    const float* ff2_b        = (const float*)d_in[14];
    const float* ln2_w        = (const float*)d_in[15];
    const float* ln2_b        = (const float*)d_in[16];
    const float* head_w       = (const float*)d_in[17];
    const float* head_b       = (const float*)d_in[18];
    const float* conf_w       = (const float*)d_in[19];
    const float* conf_b       = (const float*)d_in[20];
    float* out = (float*)d_out;

    // ---- workspace budget: weights (25.2 MB) + per-chunk x (tok*512*2) + qkv (tok*1536*2)
    constexpr size_t NWQ = (size_t)NL_ * 1536 * 512;
    constexpr size_t NWO = (size_t)NL_ * 512 * 512;
    constexpr size_t NW1 = (size_t)NL_ * 1024 * 512;
    constexpr size_t NW2 = (size_t)NL_ * 512 * 1024;
    constexpr size_t WELEM = NWQ + NWO + NW1 + NW2;          // 12,582,912 bf16
    int nchunk = 1;
    while (nchunk < 1024) {
        size_t ct = TOK / (size_t)nchunk;
        size_t need = WELEM * 2 + ct * 2048 * 2;             // bytes
        if (need <= ws_size) break;
        nchunk <<= 1;
    }
    const size_t chunkTok = TOK / (size_t)nchunk;

    bf16* wq = (bf16*)d_ws;
    bf16* wo = wq + NWQ;
    bf16* w1 = wo + NWO;
    bf16* w2 = w1 + NW1;
    bf16* xb = w2 + NW2;                 // chunkTok x 512
    bf16* qb = xb + chunkTok * 512;      // chunkTok x 1536 (qkv / ff hidden / attn out)

    cvt4_kernel<<<(int)((WELEM + 255) / 256), 256, 0, stream>>>(
        qkv_w, wq, (int)NWQ, out_w, wo, (int)NWO,
        ff1_w, w1, (int)NW1, ff2_w, w2, (int)NW2);

    const int mg = (int)(chunkTok / 128);       // gemm grid.y
    const int lg = (int)(chunkTok / 64);        // gemm_ln grid (M=64 tiles)
    for (int c = 0; c < nchunk; ++c) {
        const int t0 = (int)(c * chunkTok);
        embed_kernel<<<(int)(chunkTok / 4), 256, 0, stream>>>(seq, lid, expert_table, layer_table,
                                                              pos_table, xb, t0);
        for (int i = 0; i < NL_; ++i) {
            gemm_kernel<false><<<dim3(12, mg), 256, 0, stream>>>(
                xb, 512, wq + (size_t)i * 1536 * 512, qkv_b + i * 1536, qb, 1536, 512);
            attn_kernel<<<(int)(chunkTok / 16), 256, 0, stream>>>(qb);
            gemm_ln_kernel<<<lg, 256, 0, stream>>>(
                qb, 1536, wo + (size_t)i * 512 * 512, out_b + i * 512, xb,
                ln1_w + i * 512, ln1_b + i * 512, 512);
            gemm_kernel<true><<<dim3(8, mg), 256, 0, stream>>>(
                xb, 512, w1 + (size_t)i * 1024 * 512, ff1_b + i * 1024, qb, 1024, 512);
            gemm_ln_kernel<<<lg, 256, 0, stream>>>(
                qb, 1024, w2 + (size_t)i * 512 * 1024, ff2_b + i * 512, xb,
                ln2_w + i * 512, ln2_b + i * 512, 1024);
        }
        head_kernel<<<(int)(chunkTok / 32), 256, 0, stream>>>(xb, lid, head_w, head_b,
                                                              conf_w, conf_b, out, t0 / 32);
    }
}

// Round 11
// 5335.109 us; speedup vs baseline: 1.7387x; 1.7387x over previous
//
#include <hip/hip_runtime.h>

typedef __bf16 bf16;
typedef bf16 bf16x8 __attribute__((ext_vector_type(8)));
typedef bf16 bf16x4 __attribute__((ext_vector_type(4)));
typedef float f32x4 __attribute__((ext_vector_type(4)));

#define B_ 4096
#define S_ 32
#define H_ 512
#define NL_ 6
constexpr size_t TOK = (size_t)B_ * S_;     // 131072 tokens

typedef __attribute__((address_space(1))) void* gas_t;
typedef __attribute__((address_space(3))) void* las_t;

__device__ __forceinline__ void async16(bf16* lds, const bf16* g) {
    // 16B per lane, LDS dest = wave-uniform base + lane*16
    __builtin_amdgcn_global_load_lds((gas_t)g, (las_t)lds, 16, 0, 0);
}

// ---------------- GEMM: C[M,N] = act(A[M,K(lda)] @ W[N,K]^T + bias) ----------------
// 128x128 tile, BK=64, 4 waves of 4x4 16x16x32 bf16 MFMA frags.
// XCD-aware remap: all n-blocks of one m-row land on one XCD (id%8 round-robin
// heuristic) -> A-tile fetched ~once per XCD. [verified r6: FETCH 135->28 MB]
template<bool RELU>
__global__ __launch_bounds__(256, 2) void gemm_kernel(
    const bf16* __restrict__ A, int lda, const bf16* __restrict__ W,
    const float* __restrict__ bias,
    bf16* C, int N, int K)
{
    __shared__ __align__(16) bf16 As[128 * 64];
    __shared__ __align__(16) bf16 Bs[128 * 64];
    const int tid  = threadIdx.x;
    const int lane = tid & 63, wid = tid >> 6;
    int m_idx, n_idx;
    {
        const int nb = gridDim.x, mgd = gridDim.y;
        if ((mgd & 7) == 0) {
            int id  = blockIdx.y * nb + blockIdx.x;
            int xcd = id & 7, j = id >> 3;
            n_idx = j % nb;
            m_idx = (j / nb) * 8 + xcd;     // same-m group stays on one XCD
        } else { m_idx = blockIdx.y; n_idx = blockIdx.x; }
    }
    const int m0 = m_idx << 7, n0 = n_idx << 7;
    const int r = lane & 15, quad = lane >> 4;
    const int wm = (wid & 1) << 6, wn = (wid >> 1) << 6;

    f32x4 acc[4][4];
#pragma unroll
    for (int i = 0; i < 4; ++i)
#pragma unroll
        for (int j = 0; j < 4; ++j) acc[i][j] = {0.f, 0.f, 0.f, 0.f};

    const int nkt = K >> 6;
    for (int kt = 0; kt < nkt; ++kt) {
        const int k0 = kt << 6;
#pragma unroll
        for (int p = 0; p < 4; ++p) {
            int q   = p * 256 + tid;
            int row = q >> 3;
            int cg  = (q & 7) ^ (row & 7);
            async16(&As[(size_t)(p * 256 + wid * 64) * 8],
                    A + (size_t)(m0 + row) * lda + k0 + cg * 8);
            async16(&Bs[(size_t)(p * 256 + wid * 64) * 8],
                    W + (size_t)(n0 + row) * K + k0 + cg * 8);
        }
        __syncthreads();
#pragma unroll
        for (int ks = 0; ks < 2; ++ks) {
            bf16x8 af[4], bfr[4];
#pragma unroll
            for (int mi = 0; mi < 4; ++mi) {
                int row  = wm + mi * 16 + r;
                int slot = (ks * 4 + quad) ^ (row & 7);
                af[mi] = *(const bf16x8*)&As[row * 64 + slot * 8];
            }
#pragma unroll
            for (int ni = 0; ni < 4; ++ni) {
                int row  = wn + ni * 16 + r;
                int slot = (ks * 4 + quad) ^ (row & 7);
                bfr[ni] = *(const bf16x8*)&Bs[row * 64 + slot * 8];
            }
#pragma unroll
            for (int mi = 0; mi < 4; ++mi)
#pragma unroll
                for (int ni = 0; ni < 4; ++ni)
                    acc[mi][ni] = __builtin_amdgcn_mfma_f32_16x16x32_bf16(
                        af[mi], bfr[ni], acc[mi][ni], 0, 0, 0);
        }
        __syncthreads();
    }
    // epilogue: C/D layout col = lane&15, row = quad*4 + reg
#pragma unroll
    for (int ni = 0; ni < 4; ++ni) {
        int col  = n0 + wn + ni * 16 + r;
        float bv = bias[col];
#pragma unroll
        for (int mi = 0; mi < 4; ++mi) {
            int mrow = m0 + wm + mi * 16 + quad * 4;
#pragma unroll
            for (int rr = 0; rr < 4; ++rr) {
                size_t idx = (size_t)(mrow + rr) * N + col;
                float v = acc[mi][ni][rr] + bv;
                if (RELU) v = fmaxf(v, 0.f);
                C[idx] = (bf16)v;
            }
        }
    }
}

// ------- GEMM + residual + LayerNorm fused: x = LN(A@W^T + bias + x) -------
// M=64 tile, FULL N=512 per block, BK=64. 256 threads = 4 waves; wave w owns
// n-strip [w*128, w*128+128) over all 64 rows: acc[4][8]. 74 KB LDS -> 2
// blocks/CU. [r8 A/B: 512-thread variant -200us (8-wave barriers, no extra
// blocks); r10 A/B: BK=32 variant -4ms (2x barriers, MfmaUtil 20->11%).
// BK=64 / 4-wave is the local optimum of this 2-barrier K-loop family.]
__global__ __launch_bounds__(256, 2) void gemm_ln_kernel(
    const bf16* __restrict__ A, int lda, const bf16* __restrict__ W,
    const float* __restrict__ bias, bf16* x,
    const float* __restrict__ lnw, const float* __restrict__ lnb, int K)
{
    __shared__ __align__(16) bf16 As[64 * 64];    // 8 KB
    __shared__ __align__(16) bf16 Ws[512 * 64];   // 64 KB
    __shared__ float ps[64][4], ps2[64][4];       // 2 KB
    const int tid  = threadIdx.x;
    const int lane = tid & 63, wid = tid >> 6;
    const int m0 = blockIdx.x << 6;
    const int r = lane & 15, quad = lane >> 4;
    const int wn = wid << 7;

    f32x4 acc[4][8];
#pragma unroll
    for (int i = 0; i < 4; ++i)
#pragma unroll
        for (int j = 0; j < 8; ++j) acc[i][j] = {0.f, 0.f, 0.f, 0.f};

    const int nkt = K >> 6;
    for (int kt = 0; kt < nkt; ++kt) {
        const int k0 = kt << 6;
#pragma unroll
        for (int p = 0; p < 2; ++p) {   // A tile: 64 rows x 8 chunks of 16B
            int q   = p * 256 + tid;
            int row = q >> 3;
            int cg  = (q & 7) ^ (row & 7);
            async16(&As[(size_t)(p * 256 + wid * 64) * 8],
                    A + (size_t)(m0 + row) * lda + k0 + cg * 8);
        }
#pragma unroll
        for (int p = 0; p < 16; ++p) {  // W tile: 512 rows x 8 chunks
            int q   = p * 256 + tid;
            int row = q >> 3;
            int cg  = (q & 7) ^ (row & 7);
            async16(&Ws[(size_t)(p * 256 + wid * 64) * 8],
                    W + (size_t)row * K + k0 + cg * 8);
        }
        __syncthreads();
#pragma unroll
        for (int ks = 0; ks < 2; ++ks) {
            bf16x8 af[4], wf[8];
#pragma unroll
            for (int mi = 0; mi < 4; ++mi) {
                int row  = mi * 16 + r;
                int slot = (ks * 4 + quad) ^ (row & 7);
                af[mi] = *(const bf16x8*)&As[row * 64 + slot * 8];
            }
#pragma unroll
            for (int ni = 0; ni < 8; ++ni) {
                int row  = wn + ni * 16 + r;
                int slot = (ks * 4 + quad) ^ (row & 7);
                wf[ni] = *(const bf16x8*)&Ws[row * 64 + slot * 8];
            }
#pragma unroll
            for (int mi = 0; mi < 4; ++mi)
#pragma unroll
                for (int ni = 0; ni < 8; ++ni)
                    acc[mi][ni] = __builtin_amdgcn_mfma_f32_16x16x32_bf16(
                        af[mi], wf[ni], acc[mi][ni], 0, 0, 0);
        }
        __syncthreads();
    }

    // ---- phase 1: v = gemm + bias + residual; per-row partial sums ----
#pragma unroll
    for (int mi = 0; mi < 4; ++mi)
#pragma unroll
        for (int rr = 0; rr < 4; ++rr) {
            int row  = mi * 16 + quad * 4 + rr;      // 0..63
            float s = 0.f, s2 = 0.f;
#pragma unroll
            for (int ni = 0; ni < 8; ++ni) {
                int col = wn + ni * 16 + r;
                float v = acc[mi][ni][rr] + bias[col]
                        + (float)x[(size_t)(m0 + row) * H_ + col];
                acc[mi][ni][rr] = v;
                s += v; s2 += v * v;
            }
#pragma unroll
            for (int off = 8; off >= 1; off >>= 1) {
                s  += __shfl_xor(s,  off, 16);
                s2 += __shfl_xor(s2, off, 16);
            }
            if (r == 0) { ps[row][wid] = s; ps2[row][wid] = s2; }
        }
    __syncthreads();

    // ---- phase 2: normalize + write ----
#pragma unroll
    for (int mi = 0; mi < 4; ++mi)
#pragma unroll
        for (int rr = 0; rr < 4; ++rr) {
            int row = mi * 16 + quad * 4 + rr;
            float s  = ps[row][0] + ps[row][1] + ps[row][2] + ps[row][3];
            float s2 = ps2[row][0] + ps2[row][1] + ps2[row][2] + ps2[row][3];
            float mu  = s * (1.f / 512.f);
            float var = s2 * (1.f / 512.f) - mu * mu;
            float inv = rsqrtf(var + 1e-5f);
#pragma unroll
            for (int ni = 0; ni < 8; ++ni) {
                int col = wn + ni * 16 + r;
                float v = (acc[mi][ni][rr] - mu) * inv * lnw[col] + lnb[col];
                x[(size_t)(m0 + row) * H_ + col] = (bf16)v;
            }
        }
}

// ---------------- Attention: one wave per (b,h), S=32, HD=64 ----------------
// Round-6 version (global V gather; LDS-transpose variant had unfixable 8-way
// bank conflicts because async16 forbids padding the staged layout).
__global__ __launch_bounds__(256) void attn_kernel(bf16* qkv)
{
    __shared__ __align__(16) bf16 Pl[4][32][40];  // padded rows (80B) -> 2-way only
    __shared__ float rs[4][32];
    const int tid = threadIdx.x;
    const int lane = tid & 63, wid = tid >> 6;
    const int pair = blockIdx.x * 4 + wid;   // b_local*8 + h
    const int b = pair >> 3, h = pair & 7;
    const int r = lane & 15, quad = lane >> 4;
    bf16* base = qkv + (size_t)b * 32 * 1536 + h * 64;

    // Q as A-operand, K as B-operand (both: row = lane&15, k = quad*8+j)
    bf16x8 aq[2][2], bk[2][2];
#pragma unroll
    for (int t = 0; t < 2; ++t)
#pragma unroll
        for (int ks = 0; ks < 2; ++ks) {
            aq[t][ks] = *(const bf16x8*)(base +       (size_t)(t * 16 + r) * 1536 + ks * 32 + quad * 8);
            bk[t][ks] = *(const bf16x8*)(base + 512 + (size_t)(t * 16 + r) * 1536 + ks * 32 + quad * 8);
        }
    f32x4 sc[2][2];
#pragma unroll
    for (int mt = 0; mt < 2; ++mt)
#pragma unroll
        for (int nt = 0; nt < 2; ++nt) sc[mt][nt] = {0.f, 0.f, 0.f, 0.f};
#pragma unroll
    for (int mt = 0; mt < 2; ++mt)
#pragma unroll
        for (int nt = 0; nt < 2; ++nt)
#pragma unroll
            for (int ks = 0; ks < 2; ++ks)
                sc[mt][nt] = __builtin_amdgcn_mfma_f32_16x16x32_bf16(
                    aq[mt][ks], bk[nt][ks], sc[mt][nt], 0, 0, 0);

    // softmax over j (row i = mt*16 + quad*4 + rr lives in one 16-lane group)
#pragma unroll
    for (int mt = 0; mt < 2; ++mt)
#pragma unroll
        for (int rr = 0; rr < 4; ++rr) {
            int i = mt * 16 + quad * 4 + rr;
            float v0 = sc[mt][0][rr] * 0.125f;
            float v1 = sc[mt][1][rr] * 0.125f;
            float mx = fmaxf(v0, v1);
#pragma unroll
            for (int off = 8; off >= 1; off >>= 1) mx = fmaxf(mx, __shfl_xor(mx, off, 16));
            float e0 = __expf(v0 - mx), e1 = __expf(v1 - mx);
            float s = e0 + e1;
#pragma unroll
            for (int off = 8; off >= 1; off >>= 1) s += __shfl_xor(s, off, 16);
            Pl[wid][i][r]      = (bf16)e0;
            Pl[wid][i][r + 16] = (bf16)e1;
            if (r == 0) rs[wid][i] = s;
        }
    __syncthreads();

    // O^T = V^T (A-op, gathered from global) x P^T (B-op from LDS)
    const bf16* vb = base + 1024;
    bf16x8 av[4];
#pragma unroll
    for (int mt = 0; mt < 4; ++mt)
#pragma unroll
        for (int jj = 0; jj < 8; ++jj)
            av[mt][jj] = vb[(size_t)(quad * 8 + jj) * 1536 + mt * 16 + r];
    bf16x8 bp[2];
#pragma unroll
    for (int nt = 0; nt < 2; ++nt)
        bp[nt] = *(const bf16x8*)&Pl[wid][nt * 16 + r][quad * 8];
    f32x4 oc[4][2];
#pragma unroll
    for (int mt = 0; mt < 4; ++mt)
#pragma unroll
        for (int nt = 0; nt < 2; ++nt) oc[mt][nt] = {0.f, 0.f, 0.f, 0.f};
#pragma unroll
    for (int mt = 0; mt < 4; ++mt)
#pragma unroll
        for (int nt = 0; nt < 2; ++nt)
            oc[mt][nt] = __builtin_amdgcn_mfma_f32_16x16x32_bf16(av[mt], bp[nt], oc[mt][nt], 0, 0, 0);

    float inv0 = 1.f / rs[wid][r];
    float inv1 = 1.f / rs[wid][r + 16];
    bf16* ob = base;                          // write O into the q-slot, stride 1536
#pragma unroll
    for (int mt = 0; mt < 4; ++mt)
#pragma unroll
        for (int nt = 0; nt < 2; ++nt) {
            int i = nt * 16 + r;              // query index
            float invv = nt ? inv1 : inv0;
            bf16x4 pk;
#pragma unroll
            for (int rr = 0; rr < 4; ++rr) pk[rr] = (bf16)(oc[mt][nt][rr] * invv);
            *(bf16x4*)(ob + (size_t)i * 1536 + mt * 16 + quad * 4) = pk;  // d = mt*16+quad*4+rr
        }
}

// ---------------- Embedding sum -> bf16 x (chunk-local), 4 rows/block ----------------
__global__ __launch_bounds__(256) void embed_kernel(
    const int* __restrict__ seq, const int* __restrict__ lid,
    const float* __restrict__ et, const float* __restrict__ lt, const float* __restrict__ pt,
    bf16* __restrict__ x, int t0)
{
    const int lane = threadIdx.x & 63, wid = threadIdx.x >> 6;
    const int rowl = blockIdx.x * 4 + wid;     // chunk-local token
    const int rowg = t0 + rowl;                // global token = b*32 + s
    const int b = rowg >> 5, s = rowg & 31;
    const int e = seq[rowg];
    const int l = lid[b];
    const float* pe = et + (size_t)e * H_ + lane * 8;
    const float* pl = lt + (size_t)l * H_ + lane * 8;
    const float* pp = pt + (size_t)s * H_ + lane * 8;
    bf16x8 o8;
#pragma unroll
    for (int j = 0; j < 8; ++j) o8[j] = (bf16)(pe[j] + pl[j] + pp[j]);
    *(bf16x8*)(x + (size_t)rowl * H_ + lane * 8) = o8;
}

// ---------------- Weight convert: all 4 arrays in one dispatch ----------------
__global__ __launch_bounds__(256) void cvt4_kernel(
    const float* __restrict__ a0, bf16* __restrict__ o0, int n0,
    const float* __restrict__ a1, bf16* __restrict__ o1, int n1,
    const float* __restrict__ a2, bf16* __restrict__ o2, int n2,
    const float* __restrict__ a3, bf16* __restrict__ o3, int n3)
{
    int i = blockIdx.x * 256 + threadIdx.x;
    if (i < n0) { o0[i] = (bf16)a0[i]; }
    i -= n0;
    if (i >= 0 && i < n1) { o1[i] = (bf16)a1[i]; }
    i -= n1;
    if (i >= 0 && i < n2) { o2[i] = (bf16)a2[i]; }
    i -= n2;
    if (i >= 0 && i < n3) { o3[i] = (bf16)a3[i]; }
}

// ---------------- Head + confidence (chunk-local x, global b = b0 + blockIdx.x) -------------
__global__ __launch_bounds__(256) void head_kernel(
    const bf16* __restrict__ x, const int* __restrict__ lid,
    const float* __restrict__ hw, const float* __restrict__ hb,
    const float* __restrict__ cw, const float* __restrict__ cb, float* __restrict__ out, int b0)
{
    __shared__ float last[512];
    __shared__ float part[256];
    const int bl = blockIdx.x, tid = threadIdx.x;
    const int b = b0 + bl;
    const size_t row = (size_t)bl * 32 + 31;
    for (int c = tid; c < 512; c += 256) last[c] = (float)x[row * 512 + c];
    __syncthreads();
    int l = lid[b];
    int hidx = (l & 1) ? ((l - 1) >> 1) : 0;
    int e = tid & 127, half = tid >> 7;
    const float* wr = hw + ((size_t)hidx * 128 + e) * 512 + half * 256;
    float s = 0.f;
    for (int k = 0; k < 256; ++k) s += last[half * 256 + k] * wr[k];
    part[tid] = s;
    __syncthreads();
    if (tid < 128) out[(size_t)b * 128 + tid] = part[tid] + part[tid + 128] + hb[hidx * 128 + tid];
    if (tid >= 128 && tid < 192) {      // wave 2: confidence
        int ln = tid - 128;
        float cs = 0.f;
#pragma unroll
        for (int k = 0; k < 8; ++k) cs += last[ln * 8 + k] * cw[ln * 8 + k];
#pragma unroll
        for (int off = 32; off >= 1; off >>= 1) cs += __shfl_xor(cs, off, 64);
        if (ln == 0) out[(size_t)B_ * 128 + b] = 1.f / (1.f + __expf(-(cs + cb[0])));
    }
}

extern "C" void kernel_launch(void* const* d_in, const int* in_sizes, int n_in,
                              void* d_out, int out_size, void* d_ws, size_t ws_size,
                              hipStream_t stream)
{
    const int*   seq          = (const int*)d_in[0];
    const int*   lid          = (const int*)d_in[1];
    const float* expert_table = (const float*)d_in[2];
    const float* layer_table  = (const float*)d_in[3];
    const float* pos_table    = (const float*)d_in[4];
    const float* qkv_w        = (const float*)d_in[5];
    const float* qkv_b        = (const float*)d_in[6];
    const float* out_w        = (const float*)d_in[7];
    const float* out_b        = (const float*)d_in[8];
    const float* ln1_w        = (const float*)d_in[9];
    const float* ln1_b        = (const float*)d_in[10];
    const float* ff1_w        = (const float*)d_in[11];
    const float* ff1_b        = (const float*)d_in[12];
    const float* ff2_w        = (const float*)d_in[13];
    const float* ff2_b        = (const float*)d_in[14];
    const float* ln2_w        = (const float*)d_in[15];
    const float* ln2_b        = (const float*)d_in[16];
    const float* head_w       = (const float*)d_in[17];
    const float* head_b       = (const float*)d_in[18];
    const float* conf_w       = (const float*)d_in[19];
    const float* conf_b       = (const float*)d_in[20];
    float* out = (float*)d_out;

    // ---- workspace budget: weights (25.2 MB) + per-chunk x (tok*512*2) + qkv (tok*1536*2)
    constexpr size_t NWQ = (size_t)NL_ * 1536 * 512;
    constexpr size_t NWO = (size_t)NL_ * 512 * 512;
    constexpr size_t NW1 = (size_t)NL_ * 1024 * 512;
    constexpr size_t NW2 = (size_t)NL_ * 512 * 1024;
    constexpr size_t WELEM = NWQ + NWO + NW1 + NW2;          // 12,582,912 bf16
    int nchunk = 1;
    while (nchunk < 1024) {
        size_t ct = TOK / (size_t)nchunk;
        size_t need = WELEM * 2 + ct * 2048 * 2;             // bytes
        if (need <= ws_size) break;
        nchunk <<= 1;
    }
    const size_t chunkTok = TOK / (size_t)nchunk;

    bf16* wq = (bf16*)d_ws;
    bf16* wo = wq + NWQ;
    bf16* w1 = wo + NWO;
    bf16* w2 = w1 + NW1;
    bf16* xb = w2 + NW2;                 // chunkTok x 512
    bf16* qb = xb + chunkTok * 512;      // chunkTok x 1536 (qkv / ff hidden / attn out)

    cvt4_kernel<<<(int)((WELEM + 255) / 256), 256, 0, stream>>>(
        qkv_w, wq, (int)NWQ, out_w, wo, (int)NWO,
        ff1_w, w1, (int)NW1, ff2_w, w2, (int)NW2);

    const int mg = (int)(chunkTok / 128);       // gemm grid.y
    const int lg = (int)(chunkTok / 64);        // gemm_ln grid (M=64 tiles)
    for (int c = 0; c < nchunk; ++c) {
        const int t0 = (int)(c * chunkTok);
        embed_kernel<<<(int)(chunkTok / 4), 256, 0, stream>>>(seq, lid, expert_table, layer_table,
                                                              pos_table, xb, t0);
        for (int i = 0; i < NL_; ++i) {
            gemm_kernel<false><<<dim3(12, mg), 256, 0, stream>>>(
                xb, 512, wq + (size_t)i * 1536 * 512, qkv_b + i * 1536, qb, 1536, 512);
            attn_kernel<<<(int)(chunkTok / 16), 256, 0, stream>>>(qb);
            gemm_ln_kernel<<<lg, 256, 0, stream>>>(
                qb, 1536, wo + (size_t)i * 512 * 512, out_b + i * 512, xb,
                ln1_w + i * 512, ln1_b + i * 512, 512);
            gemm_kernel<true><<<dim3(8, mg), 256, 0, stream>>>(
                xb, 512, w1 + (size_t)i * 1024 * 512, ff1_b + i * 1024, qb, 1024, 512);
            gemm_ln_kernel<<<lg, 256, 0, stream>>>(
                qb, 1024, w2 + (size_t)i * 512 * 1024, ff2_b + i * 512, xb,
                ln2_w + i * 512, ln2_b + i * 512, 1024);
        }
        head_kernel<<<(int)(chunkTok / 32), 256, 0, stream>>>(xb, lid, head_w, head_b,
                                                              conf_w, conf_b, out, t0 / 32);
    }
}

// Round 12
// 4986.933 us; speedup vs baseline: 1.8601x; 1.0698x over previous
//
#include <hip/hip_runtime.h>

typedef __bf16 bf16;
typedef bf16 bf16x8 __attribute__((ext_vector_type(8)));
typedef bf16 bf16x4 __attribute__((ext_vector_type(4)));
typedef float f32x4 __attribute__((ext_vector_type(4)));

#define B_ 4096
#define S_ 32
#define H_ 512
#define NL_ 6
constexpr size_t TOK = (size_t)B_ * S_;     // 131072 tokens

typedef __attribute__((address_space(1))) void* gas_t;
typedef __attribute__((address_space(3))) void* las_t;

__device__ __forceinline__ void async16(bf16* lds, const bf16* g) {
    // 16B per lane, LDS dest = wave-uniform base + lane*16
    __builtin_amdgcn_global_load_lds((gas_t)g, (las_t)lds, 16, 0, 0);
}

// ---------------- GEMM: C[M,N(ldc)] = act(A[M,K(lda)] @ W[N,K]^T + bias) ----------------
// 128x128 tile, BK=64, 4 waves of 4x4 16x16x32 bf16 MFMA frags.
// XCD-aware remap: all n-blocks of one m-row land on one XCD (id%8 round-robin
// heuristic) -> A-tile fetched ~once per XCD. [verified r6: FETCH 135->28 MB]
template<bool RELU>
__global__ __launch_bounds__(256, 2) void gemm_kernel(
    const bf16* __restrict__ A, int lda, const bf16* __restrict__ W,
    const float* __restrict__ bias,
    bf16* C, int ldc, int K)
{
    __shared__ __align__(16) bf16 As[128 * 64];
    __shared__ __align__(16) bf16 Bs[128 * 64];
    const int tid  = threadIdx.x;
    const int lane = tid & 63, wid = tid >> 6;
    int m_idx, n_idx;
    {
        const int nb = gridDim.x, mgd = gridDim.y;
        if ((mgd & 7) == 0) {
            int id  = blockIdx.y * nb + blockIdx.x;
            int xcd = id & 7, j = id >> 3;
            n_idx = j % nb;
            m_idx = (j / nb) * 8 + xcd;     // same-m group stays on one XCD
        } else { m_idx = blockIdx.y; n_idx = blockIdx.x; }
    }
    const int m0 = m_idx << 7, n0 = n_idx << 7;
    const int r = lane & 15, quad = lane >> 4;
    const int wm = (wid & 1) << 6, wn = (wid >> 1) << 6;

    f32x4 acc[4][4];
#pragma unroll
    for (int i = 0; i < 4; ++i)
#pragma unroll
        for (int j = 0; j < 4; ++j) acc[i][j] = {0.f, 0.f, 0.f, 0.f};

    const int nkt = K >> 6;
    for (int kt = 0; kt < nkt; ++kt) {
        const int k0 = kt << 6;
#pragma unroll
        for (int p = 0; p < 4; ++p) {
            int q   = p * 256 + tid;
            int row = q >> 3;
            int cg  = (q & 7) ^ (row & 7);
            async16(&As[(size_t)(p * 256 + wid * 64) * 8],
                    A + (size_t)(m0 + row) * lda + k0 + cg * 8);
            async16(&Bs[(size_t)(p * 256 + wid * 64) * 8],
                    W + (size_t)(n0 + row) * K + k0 + cg * 8);
        }
        __syncthreads();
#pragma unroll
        for (int ks = 0; ks < 2; ++ks) {
            bf16x8 af[4], bfr[4];
#pragma unroll
            for (int mi = 0; mi < 4; ++mi) {
                int row  = wm + mi * 16 + r;
                int slot = (ks * 4 + quad) ^ (row & 7);
                af[mi] = *(const bf16x8*)&As[row * 64 + slot * 8];
            }
#pragma unroll
            for (int ni = 0; ni < 4; ++ni) {
                int row  = wn + ni * 16 + r;
                int slot = (ks * 4 + quad) ^ (row & 7);
                bfr[ni] = *(const bf16x8*)&Bs[row * 64 + slot * 8];
            }
#pragma unroll
            for (int mi = 0; mi < 4; ++mi)
#pragma unroll
                for (int ni = 0; ni < 4; ++ni)
                    acc[mi][ni] = __builtin_amdgcn_mfma_f32_16x16x32_bf16(
                        af[mi], bfr[ni], acc[mi][ni], 0, 0, 0);
        }
        __syncthreads();
    }
    // epilogue: C/D layout col = lane&15, row = quad*4 + reg
#pragma unroll
    for (int ni = 0; ni < 4; ++ni) {
        int col  = n0 + wn + ni * 16 + r;
        float bv = bias[col];
#pragma unroll
        for (int mi = 0; mi < 4; ++mi) {
            int mrow = m0 + wm + mi * 16 + quad * 4;
#pragma unroll
            for (int rr = 0; rr < 4; ++rr) {
                size_t idx = (size_t)(mrow + rr) * ldc + col;
                float v = acc[mi][ni][rr] + bv;
                if (RELU) v = fmaxf(v, 0.f);
                C[idx] = (bf16)v;
            }
        }
    }
}

// ------- GEMM + residual + LayerNorm fused: x = LN(A@W^T + bias + x) -------
// M=64 tile, FULL N=512 per block, BK=64. 256 threads = 4 waves; wave w owns
// n-strip [w*128, w*128+128) over all 64 rows: acc[4][8]. 74 KB LDS -> 2
// blocks/CU. [r8 A/B: 512-thread variant -200us; r10 A/B: BK=32 variant -4ms.
// BK=64 / 4-wave is the local optimum of this 2-barrier K-loop family.]
// x rows at stride ldx (gathered last-token views pass ldx=16384).
__global__ __launch_bounds__(256, 2) void gemm_ln_kernel(
    const bf16* __restrict__ A, int lda, const bf16* __restrict__ W,
    const float* __restrict__ bias, bf16* x, int ldx,
    const float* __restrict__ lnw, const float* __restrict__ lnb, int K)
{
    __shared__ __align__(16) bf16 As[64 * 64];    // 8 KB
    __shared__ __align__(16) bf16 Ws[512 * 64];   // 64 KB
    __shared__ float ps[64][4], ps2[64][4];       // 2 KB
    const int tid  = threadIdx.x;
    const int lane = tid & 63, wid = tid >> 6;
    const int m0 = blockIdx.x << 6;
    const int r = lane & 15, quad = lane >> 4;
    const int wn = wid << 7;

    f32x4 acc[4][8];
#pragma unroll
    for (int i = 0; i < 4; ++i)
#pragma unroll
        for (int j = 0; j < 8; ++j) acc[i][j] = {0.f, 0.f, 0.f, 0.f};

    const int nkt = K >> 6;
    for (int kt = 0; kt < nkt; ++kt) {
        const int k0 = kt << 6;
#pragma unroll
        for (int p = 0; p < 2; ++p) {   // A tile: 64 rows x 8 chunks of 16B
            int q   = p * 256 + tid;
            int row = q >> 3;
            int cg  = (q & 7) ^ (row & 7);
            async16(&As[(size_t)(p * 256 + wid * 64) * 8],
                    A + (size_t)(m0 + row) * lda + k0 + cg * 8);
        }
#pragma unroll
        for (int p = 0; p < 16; ++p) {  // W tile: 512 rows x 8 chunks
            int q   = p * 256 + tid;
            int row = q >> 3;
            int cg  = (q & 7) ^ (row & 7);
            async16(&Ws[(size_t)(p * 256 + wid * 64) * 8],
                    W + (size_t)row * K + k0 + cg * 8);
        }
        __syncthreads();
#pragma unroll
        for (int ks = 0; ks < 2; ++ks) {
            bf16x8 af[4], wf[8];
#pragma unroll
            for (int mi = 0; mi < 4; ++mi) {
                int row  = mi * 16 + r;
                int slot = (ks * 4 + quad) ^ (row & 7);
                af[mi] = *(const bf16x8*)&As[row * 64 + slot * 8];
            }
#pragma unroll
            for (int ni = 0; ni < 8; ++ni) {
                int row  = wn + ni * 16 + r;
                int slot = (ks * 4 + quad) ^ (row & 7);
                wf[ni] = *(const bf16x8*)&Ws[row * 64 + slot * 8];
            }
#pragma unroll
            for (int mi = 0; mi < 4; ++mi)
#pragma unroll
                for (int ni = 0; ni < 8; ++ni)
                    acc[mi][ni] = __builtin_amdgcn_mfma_f32_16x16x32_bf16(
                        af[mi], wf[ni], acc[mi][ni], 0, 0, 0);
        }
        __syncthreads();
    }

    // ---- phase 1: v = gemm + bias + residual; per-row partial sums ----
#pragma unroll
    for (int mi = 0; mi < 4; ++mi)
#pragma unroll
        for (int rr = 0; rr < 4; ++rr) {
            int row  = mi * 16 + quad * 4 + rr;      // 0..63
            float s = 0.f, s2 = 0.f;
#pragma unroll
            for (int ni = 0; ni < 8; ++ni) {
                int col = wn + ni * 16 + r;
                float v = acc[mi][ni][rr] + bias[col]
                        + (float)x[(size_t)(m0 + row) * ldx + col];
                acc[mi][ni][rr] = v;
                s += v; s2 += v * v;
            }
#pragma unroll
            for (int off = 8; off >= 1; off >>= 1) {
                s  += __shfl_xor(s,  off, 16);
                s2 += __shfl_xor(s2, off, 16);
            }
            if (r == 0) { ps[row][wid] = s; ps2[row][wid] = s2; }
        }
    __syncthreads();

    // ---- phase 2: normalize + write ----
#pragma unroll
    for (int mi = 0; mi < 4; ++mi)
#pragma unroll
        for (int rr = 0; rr < 4; ++rr) {
            int row = mi * 16 + quad * 4 + rr;
            float s  = ps[row][0] + ps[row][1] + ps[row][2] + ps[row][3];
            float s2 = ps2[row][0] + ps2[row][1] + ps2[row][2] + ps2[row][3];
            float mu  = s * (1.f / 512.f);
            float var = s2 * (1.f / 512.f) - mu * mu;
            float inv = rsqrtf(var + 1e-5f);
#pragma unroll
            for (int ni = 0; ni < 8; ++ni) {
                int col = wn + ni * 16 + r;
                float v = (acc[mi][ni][rr] - mu) * inv * lnw[col] + lnb[col];
                x[(size_t)(m0 + row) * ldx + col] = (bf16)v;
            }
        }
}

// ---------------- Attention: one wave per (b,h), S=32, HD=64 ----------------
// Round-6 version (global V gather; LDS-transpose variant had unfixable 8-way
// bank conflicts because async16 forbids padding the staged layout).
__global__ __launch_bounds__(256) void attn_kernel(bf16* qkv)
{
    __shared__ __align__(16) bf16 Pl[4][32][40];  // padded rows (80B) -> 2-way only
    __shared__ float rs[4][32];
    const int tid = threadIdx.x;
    const int lane = tid & 63, wid = tid >> 6;
    const int pair = blockIdx.x * 4 + wid;   // b_local*8 + h
    const int b = pair >> 3, h = pair & 7;
    const int r = lane & 15, quad = lane >> 4;
    bf16* base = qkv + (size_t)b * 32 * 1536 + h * 64;

    // Q as A-operand, K as B-operand (both: row = lane&15, k = quad*8+j)
    bf16x8 aq[2][2], bk[2][2];
#pragma unroll
    for (int t = 0; t < 2; ++t)
#pragma unroll
        for (int ks = 0; ks < 2; ++ks) {
            aq[t][ks] = *(const bf16x8*)(base +       (size_t)(t * 16 + r) * 1536 + ks * 32 + quad * 8);
            bk[t][ks] = *(const bf16x8*)(base + 512 + (size_t)(t * 16 + r) * 1536 + ks * 32 + quad * 8);
        }
    f32x4 sc[2][2];
#pragma unroll
    for (int mt = 0; mt < 2; ++mt)
#pragma unroll
        for (int nt = 0; nt < 2; ++nt) sc[mt][nt] = {0.f, 0.f, 0.f, 0.f};
#pragma unroll
    for (int mt = 0; mt < 2; ++mt)
#pragma unroll
        for (int nt = 0; nt < 2; ++nt)
#pragma unroll
            for (int ks = 0; ks < 2; ++ks)
                sc[mt][nt] = __builtin_amdgcn_mfma_f32_16x16x32_bf16(
                    aq[mt][ks], bk[nt][ks], sc[mt][nt], 0, 0, 0);

    // softmax over j (row i = mt*16 + quad*4 + rr lives in one 16-lane group)
#pragma unroll
    for (int mt = 0; mt < 2; ++mt)
#pragma unroll
        for (int rr = 0; rr < 4; ++rr) {
            int i = mt * 16 + quad * 4 + rr;
            float v0 = sc[mt][0][rr] * 0.125f;
            float v1 = sc[mt][1][rr] * 0.125f;
            float mx = fmaxf(v0, v1);
#pragma unroll
            for (int off = 8; off >= 1; off >>= 1) mx = fmaxf(mx, __shfl_xor(mx, off, 16));
            float e0 = __expf(v0 - mx), e1 = __expf(v1 - mx);
            float s = e0 + e1;
#pragma unroll
            for (int off = 8; off >= 1; off >>= 1) s += __shfl_xor(s, off, 16);
            Pl[wid][i][r]      = (bf16)e0;
            Pl[wid][i][r + 16] = (bf16)e1;
            if (r == 0) rs[wid][i] = s;
        }
    __syncthreads();

    // O^T = V^T (A-op, gathered from global) x P^T (B-op from LDS)
    const bf16* vb = base + 1024;
    bf16x8 av[4];
#pragma unroll
    for (int mt = 0; mt < 4; ++mt)
#pragma unroll
        for (int jj = 0; jj < 8; ++jj)
            av[mt][jj] = vb[(size_t)(quad * 8 + jj) * 1536 + mt * 16 + r];
    bf16x8 bp[2];
#pragma unroll
    for (int nt = 0; nt < 2; ++nt)
        bp[nt] = *(const bf16x8*)&Pl[wid][nt * 16 + r][quad * 8];
    f32x4 oc[4][2];
#pragma unroll
    for (int mt = 0; mt < 4; ++mt)
#pragma unroll
        for (int nt = 0; nt < 2; ++nt) oc[mt][nt] = {0.f, 0.f, 0.f, 0.f};
#pragma unroll
    for (int mt = 0; mt < 4; ++mt)
#pragma unroll
        for (int nt = 0; nt < 2; ++nt)
            oc[mt][nt] = __builtin_amdgcn_mfma_f32_16x16x32_bf16(av[mt], bp[nt], oc[mt][nt], 0, 0, 0);

    float inv0 = 1.f / rs[wid][r];
    float inv1 = 1.f / rs[wid][r + 16];
    bf16* ob = base;                          // write O into the q-slot, stride 1536
#pragma unroll
    for (int mt = 0; mt < 4; ++mt)
#pragma unroll
        for (int nt = 0; nt < 2; ++nt) {
            int i = nt * 16 + r;              // query index
            float invv = nt ? inv1 : inv0;
            bf16x4 pk;
#pragma unroll
            for (int rr = 0; rr < 4; ++rr) pk[rr] = (bf16)(oc[mt][nt][rr] * invv);
            *(bf16x4*)(ob + (size_t)i * 1536 + mt * 16 + quad * 4) = pk;  // d = mt*16+quad*4+rr
        }
}

// ------- Last-layer attention: only query 31 per (b,h) matters downstream -------
// One wave per (b,h). Scores via per-lane dot (lanes 0..31 = keys), shuffle
// softmax, coalesced V accumulation (lane = d). O -> q-slot of row 31.
__global__ __launch_bounds__(256) void attn_last_kernel(bf16* qkv)
{
    const int tid = threadIdx.x;
    const int lane = tid & 63, wid = tid >> 6;
    const int pair = blockIdx.x * 4 + wid;   // b_local*8 + h
    const int b = pair >> 3, h = pair & 7;
    bf16* base = qkv + (size_t)b * 32 * 1536 + h * 64;
    const bf16* qrow = base + 31 * 1536;

    float s;
    if (lane < 32) {
        const bf16* krow = base + 512 + (size_t)lane * 1536;
        float acc = 0.f;
#pragma unroll
        for (int d = 0; d < 64; d += 8) {
            bf16x8 qv = *(const bf16x8*)(qrow + d);
            bf16x8 kv = *(const bf16x8*)(krow + d);
#pragma unroll
            for (int j = 0; j < 8; ++j) acc += (float)qv[j] * (float)kv[j];
        }
        s = acc * 0.125f;
    } else s = -1e30f;
    float mx = s;
#pragma unroll
    for (int off = 16; off >= 1; off >>= 1) mx = fmaxf(mx, __shfl_xor(mx, off, 32));
    float e = __expf(s - mx);
    float sum = e;
#pragma unroll
    for (int off = 16; off >= 1; off >>= 1) sum += __shfl_xor(sum, off, 32);

    // o_d (lane = d): coalesced 128B V row reads per j
    const bf16* vb = base + 1024;
    float o = 0.f;
#pragma unroll
    for (int j = 0; j < 32; ++j) {
        float pj = __shfl(e, j, 64);
        o += pj * (float)vb[(size_t)j * 1536 + lane];
    }
    float inv = 1.f / __shfl(sum, 0, 64);
    ((bf16*)base)[31 * 1536 + lane] = (bf16)(o * inv);
}

// ---------------- Embedding sum -> bf16 x (chunk-local), 4 rows/block ----------------
__global__ __launch_bounds__(256) void embed_kernel(
    const int* __restrict__ seq, const int* __restrict__ lid,
    const float* __restrict__ et, const float* __restrict__ lt, const float* __restrict__ pt,
    bf16* __restrict__ x, int t0)
{
    const int lane = threadIdx.x & 63, wid = threadIdx.x >> 6;
    const int rowl = blockIdx.x * 4 + wid;     // chunk-local token
    const int rowg = t0 + rowl;                // global token = b*32 + s
    const int b = rowg >> 5, s = rowg & 31;
    const int e = seq[rowg];
    const int l = lid[b];
    const float* pe = et + (size_t)e * H_ + lane * 8;
    const float* pl = lt + (size_t)l * H_ + lane * 8;
    const float* pp = pt + (size_t)s * H_ + lane * 8;
    bf16x8 o8;
#pragma unroll
    for (int j = 0; j < 8; ++j) o8[j] = (bf16)(pe[j] + pl[j] + pp[j]);
    *(bf16x8*)(x + (size_t)rowl * H_ + lane * 8) = o8;
}

// ---------------- Weight convert: all 4 arrays in one dispatch ----------------
__global__ __launch_bounds__(256) void cvt4_kernel(
    const float* __restrict__ a0, bf16* __restrict__ o0, int n0,
    const float* __restrict__ a1, bf16* __restrict__ o1, int n1,
    const float* __restrict__ a2, bf16* __restrict__ o2, int n2,
    const float* __restrict__ a3, bf16* __restrict__ o3, int n3)
{
    int i = blockIdx.x * 256 + threadIdx.x;
    if (i < n0) { o0[i] = (bf16)a0[i]; }
    i -= n0;
    if (i >= 0 && i < n1) { o1[i] = (bf16)a1[i]; }
    i -= n1;
    if (i >= 0 && i < n2) { o2[i] = (bf16)a2[i]; }
    i -= n2;
    if (i >= 0 && i < n3) { o3[i] = (bf16)a3[i]; }
}

// ---------------- Head + confidence (chunk-local x, global b = b0 + blockIdx.x) -------------
__global__ __launch_bounds__(256) void head_kernel(
    const bf16* __restrict__ x, const int* __restrict__ lid,
    const float* __restrict__ hw, const float* __restrict__ hb,
    const float* __restrict__ cw, const float* __restrict__ cb, float* __restrict__ out, int b0)
{
    __shared__ float last[512];
    __shared__ float part[256];
    const int bl = blockIdx.x, tid = threadIdx.x;
    const int b = b0 + bl;
    const size_t row = (size_t)bl * 32 + 31;
    for (int c = tid; c < 512; c += 256) last[c] = (float)x[row * 512 + c];
    __syncthreads();
    int l = lid[b];
    int hidx = (l & 1) ? ((l - 1) >> 1) : 0;
    int e = tid & 127, half = tid >> 7;
    const float* wr = hw + ((size_t)hidx * 128 + e) * 512 + half * 256;
    float s = 0.f;
    for (int k = 0; k < 256; ++k) s += last[half * 256 + k] * wr[k];
    part[tid] = s;
    __syncthreads();
    if (tid < 128) out[(size_t)b * 128 + tid] = part[tid] + part[tid + 128] + hb[hidx * 128 + tid];
    if (tid >= 128 && tid < 192) {      // wave 2: confidence
        int ln = tid - 128;
        float cs = 0.f;
#pragma unroll
        for (int k = 0; k < 8; ++k) cs += last[ln * 8 + k] * cw[ln * 8 + k];
#pragma unroll
        for (int off = 32; off >= 1; off >>= 1) cs += __shfl_xor(cs, off, 64);
        if (ln == 0) out[(size_t)B_ * 128 + b] = 1.f / (1.f + __expf(-(cs + cb[0])));
    }
}

extern "C" void kernel_launch(void* const* d_in, const int* in_sizes, int n_in,
                              void* d_out, int out_size, void* d_ws, size_t ws_size,
                              hipStream_t stream)
{
    const int*   seq          = (const int*)d_in[0];
    const int*   lid          = (const int*)d_in[1];
    const float* expert_table = (const float*)d_in[2];
    const float* layer_table  = (const float*)d_in[3];
    const float* pos_table    = (const float*)d_in[4];
    const float* qkv_w        = (const float*)d_in[5];
    const float* qkv_b        = (const float*)d_in[6];
    const float* out_w        = (const float*)d_in[7];
    const float* out_b        = (const float*)d_in[8];
    const float* ln1_w        = (const float*)d_in[9];
    const float* ln1_b        = (const float*)d_in[10];
    const float* ff1_w        = (const float*)d_in[11];
    const float* ff1_b        = (const float*)d_in[12];
    const float* ff2_w        = (const float*)d_in[13];
    const float* ff2_b        = (const float*)d_in[14];
    const float* ln2_w        = (const float*)d_in[15];
    const float* ln2_b        = (const float*)d_in[16];
    const float* head_w       = (const float*)d_in[17];
    const float* head_b       = (const float*)d_in[18];
    const float* conf_w       = (const float*)d_in[19];
    const float* conf_b       = (const float*)d_in[20];
    float* out = (float*)d_out;

    // ---- workspace budget: weights (25.2 MB) + per-chunk x (tok*512*2) + qkv (tok*1536*2)
    constexpr size_t NWQ = (size_t)NL_ * 1536 * 512;
    constexpr size_t NWO = (size_t)NL_ * 512 * 512;
    constexpr size_t NW1 = (size_t)NL_ * 1024 * 512;
    constexpr size_t NW2 = (size_t)NL_ * 512 * 1024;
    constexpr size_t WELEM = NWQ + NWO + NW1 + NW2;          // 12,582,912 bf16
    int nchunk = 1;
    while (nchunk < 1024) {
        size_t ct = TOK / (size_t)nchunk;
        size_t need = WELEM * 2 + ct * 2048 * 2;             // bytes
        if (need <= ws_size) break;
        nchunk <<= 1;
    }
    const size_t chunkTok = TOK / (size_t)nchunk;

    bf16* wq = (bf16*)d_ws;
    bf16* wo = wq + NWQ;
    bf16* w1 = wo + NWO;
    bf16* w2 = w1 + NW1;
    bf16* xb = w2 + NW2;                 // chunkTok x 512
    bf16* qb = xb + chunkTok * 512;      // chunkTok x 1536 (qkv / ff hidden / attn out)

    cvt4_kernel<<<(int)((WELEM + 255) / 256), 256, 0, stream>>>(
        qkv_w, wq, (int)NWQ, out_w, wo, (int)NWO,
        ff1_w, w1, (int)NW1, ff2_w, w2, (int)NW2);

    const int mg = (int)(chunkTok / 128);       // gemm grid.y
    const int lg = (int)(chunkTok / 64);        // gemm_ln grid (M=64 tiles)
    const bool fast = (chunkTok % 4096) == 0;   // last-layer gathered path needs M'%128==0
    const int mL = (int)(chunkTok / 32);        // gathered rows (last tokens)

    for (int c = 0; c < nchunk; ++c) {
        const int t0 = (int)(c * chunkTok);
        embed_kernel<<<(int)(chunkTok / 4), 256, 0, stream>>>(seq, lid, expert_table, layer_table,
                                                              pos_table, xb, t0);
        for (int i = 0; i < NL_; ++i) {
            const bf16* wq_i = wq + (size_t)i * 1536 * 512;
            const bf16* wo_i = wo + (size_t)i * 512 * 512;
            const bf16* w1_i = w1 + (size_t)i * 1024 * 512;
            const bf16* w2_i = w2 + (size_t)i * 512 * 1024;
            const bool last = fast && (i == NL_ - 1);
            if (!last) {
                gemm_kernel<false><<<dim3(12, mg), 256, 0, stream>>>(
                    xb, 512, wq_i, qkv_b + i * 1536, qb, 1536, 512);
                attn_kernel<<<(int)(chunkTok / 16), 256, 0, stream>>>(qb);
                gemm_ln_kernel<<<lg, 256, 0, stream>>>(
                    qb, 1536, wo_i, out_b + i * 512, xb, 512,
                    ln1_w + i * 512, ln1_b + i * 512, 512);
                gemm_kernel<true><<<dim3(8, mg), 256, 0, stream>>>(
                    xb, 512, w1_i, ff1_b + i * 1024, qb, 1024, 512);
                gemm_ln_kernel<<<lg, 256, 0, stream>>>(
                    qb, 1024, w2_i, ff2_b + i * 512, xb, 512,
                    ln2_w + i * 512, ln2_b + i * 512, 1024);
            } else {
                // K,V for ALL rows (cols 512..1536 of qkv)
                gemm_kernel<false><<<dim3(8, mg), 256, 0, stream>>>(
                    xb, 512, wq_i + (size_t)512 * 512, qkv_b + i * 1536 + 512,
                    qb + 512, 1536, 512);
                // Q only for last-token rows (gathered strided views)
                gemm_kernel<false><<<dim3(4, mL / 128), 256, 0, stream>>>(
                    xb + 31 * 512, 32 * 512, wq_i, qkv_b + i * 1536,
                    qb + (size_t)31 * 1536, 32 * 1536, 512);
                // attention: 1 query per (b,h)
                attn_last_kernel<<<(int)(chunkTok / 16), 256, 0, stream>>>(qb);
                // out-proj + LN on gathered rows
                gemm_ln_kernel<<<mL / 64, 256, 0, stream>>>(
                    qb + (size_t)31 * 1536, 32 * 1536, wo_i, out_b + i * 512,
                    xb + 31 * 512, 32 * 512,
                    ln1_w + i * 512, ln1_b + i * 512, 512);
                // ff1 on gathered rows -> hidden in dead qkv row space (cols 0..1024)
                gemm_kernel<true><<<dim3(8, mL / 128), 256, 0, stream>>>(
                    xb + 31 * 512, 32 * 512, w1_i, ff1_b + i * 1024,
                    qb + (size_t)31 * 1536, 32 * 1536, 512);
                // ff2 + LN on gathered rows
                gemm_ln_kernel<<<mL / 64, 256, 0, stream>>>(
                    qb + (size_t)31 * 1536, 32 * 1536, w2_i, ff2_b + i * 512,
                    xb + 31 * 512, 32 * 512,
                    ln2_w + i * 512, ln2_b + i * 512, 1024);
            }
        }
        head_kernel<<<(int)(chunkTok / 32), 256, 0, stream>>>(xb, lid, head_w, head_b,
                                                              conf_w, conf_b, out, t0 / 32);
    }
}